// Round 6
// baseline (219.838 us; speedup 1.0000x reference)
//
#include <hip/hip_runtime.h>
#include <hip/hip_fp16.h>

#define S_DIM 512
#define B_DIM 256
#define H_DIM 500
#define HP    512
#define M_DIM (S_DIM * B_DIM)     // 131072

typedef _Float16 half8_t __attribute__((ext_vector_type(8)));
typedef _Float16 half4_t __attribute__((ext_vector_type(4)));
typedef float    f32x4  __attribute__((ext_vector_type(4)));

// workspace layout (bytes)
#define WS_W2R 0                       // fp16 tiled [32][64][16][8] = 512 KB
#define WS_AT  (512 * 1024)            // fp32 At[h][b] [512][256]   = 512 KB
#define WS_VP  (1024 * 1024)           // fp32 [512]                 =   2 KB
#define WS_SC  (1024 * 1024 + 4096)    // fp32 sct[b][s] [256][512]  = 512 KB

// ---- prep: W2 -> fp16, fragment-tiled W2r[t=n>>4][c=k>>3][n&15][k&7]; v padded ----
__global__ void prep_w2_v(const float* __restrict__ W, const float* __restrict__ v,
                          _Float16* __restrict__ W2r, float* __restrict__ vp) {
    int idx = blockIdx.x * blockDim.x + threadIdx.x;   // 0..131071
#pragma unroll
    for (int r = 0; r < 2; ++r) {
        int e = idx + r * 131072;                      // 0..262143
        int n = e >> 9, k = e & 511;
        float val = (n < H_DIM && k < H_DIM) ? W[n * 1000 + 500 + k] : 0.0f;
        int dst = ((n >> 4) * 64 + (k >> 3)) * 128 + (n & 15) * 8 + (k & 7);
        W2r[dst] = (_Float16)val;
    }
    if (idx < HP) vp[idx] = (idx < H_DIM) ? v[idx] : 0.0f;
}

// ---- prep: At[h][b] = b_attn[h] + hidden[b,:] . W1[h,:]  (exact fp32, transposed) ----
__global__ void prep_A(const float* __restrict__ hidden, const float* __restrict__ W,
                       const float* __restrict__ b_attn, float* __restrict__ At) {
    int b = blockIdx.x;
    int t = threadIdx.x;               // 0..511 = h
    __shared__ float hs[HP];
    hs[t] = (t < H_DIM) ? hidden[b * H_DIM + t] : 0.0f;
    __syncthreads();
    float acc = 0.0f;
    if (t < H_DIM) {
        acc = b_attn[t];
        const float4* wr = (const float4*)(W + t * 1000);
        const float4* hr = (const float4*)hs;
#pragma unroll 5
        for (int i = 0; i < 125; ++i) {
            float4 w4 = wr[i], h4 = hr[i];
            acc += w4.x * h4.x + w4.y * h4.y + w4.z * h4.z + w4.w * h4.w;
        }
    }
    At[t * B_DIM + b] = acc;
}

// ---- main: BM=128 x BN=512 (full N), 512 thr = 8 waves (2M x 4N), wave 64x128.
// acc[4][8] = 128 AGPR; launch_bounds(512,2) -> 256-reg cap, no spill.
// A: LDS dbuf [2][128][32], 0-conflict swizzle, prefetch 2 k-steps ahead (regs).
// B: direct global->reg from fragment-tiled L2-resident W2r (no LDS for B).
// Raw s_barrier + lgkmcnt(0): no vmcnt drain -> loads stay in flight.
__launch_bounds__(512, 2)
__global__ void fused_attn_gemm(const float* __restrict__ enc,
                                const _Float16* __restrict__ W2r,
                                const float* __restrict__ At,
                                const float* __restrict__ vp,
                                float* __restrict__ sct) {
    __shared__ _Float16 As[2][128][32];   // 16 KB
    __shared__ float    red[4][128];      //  2 KB

    const int tid  = threadIdx.x;
    const int lane = tid & 63;
    const int wid  = tid >> 6;            // 0..7
    const int wm   = wid >> 2;            // 0..1  (M half)
    const int wn   = wid & 3;             // 0..3  (N quarter)
    const int l15  = lane & 15;
    const int lq   = lane >> 4;           // 0..3

    const int mblk  = blockIdx.x;         // 0..1023
    const int m0    = mblk * 128;
    const int s_idx = mblk >> 1;
    const int bloc  = (mblk & 1) * 128;

    // A staging: thread covers rows r0 and r0+64 at k-subchunk j (4 floats)
    const int r0 = tid >> 3;              // 0..63
    const int r1 = r0 + 64;
    const int j  = tid & 7;
    const float* gA0 = enc + (size_t)(m0 + r0) * H_DIM + j * 4;
    const float* gA1 = enc + (size_t)(m0 + r1) * H_DIM + j * 4;
    const int jt = (j < 4) ? j : 4;       // clamped tail subchunk
    const float* gT0 = enc + (size_t)(m0 + r0) * H_DIM + 480 + jt * 4;
    const float* gT1 = enc + (size_t)(m0 + r1) * H_DIM + 480 + jt * 4;
    const bool jz = (j >= 5);             // tail elements k>=500 -> zero
    // swizzled A write slot (same for r0/r1 since they differ by 64)
    const int aoff = ((j >> 1) ^ ((r0 >> 1) & 3)) * 8 + (j & 1) * 4;
    // swizzled fragment-read chunk
    const int rch = (lq ^ ((l15 >> 1) & 3)) * 8;

    // B fragment base: tile t = wn*8+nf, chunk c = ks*4+lq, row l15
    const _Float16* gB = W2r + wn * 65536 + lq * 128 + l15 * 8;

    f32x4 acc[4][8];
#pragma unroll
    for (int a = 0; a < 4; ++a)
#pragma unroll
        for (int b = 0; b < 8; ++b) acc[a][b] = 0;

    f32x4 pe0, pe1, po0, po1;             // pending A slices (ping-pong)

    auto ldA = [&](int slice, f32x4& d0, f32x4& d1) {
        if (slice == 15) { d0 = *(const f32x4*)gT0; d1 = *(const f32x4*)gT1; }
        else { d0 = *(const f32x4*)(gA0 + slice * 32); d1 = *(const f32x4*)(gA1 + slice * 32); }
    };
    auto wrA = [&](int buf, f32x4 d0, f32x4 d1, bool tail) {
        half4_t h0, h1;
#pragma unroll
        for (int u = 0; u < 4; ++u) {
            h0[u] = (tail && jz) ? (_Float16)0.0f : (_Float16)d0[u];
            h1[u] = (tail && jz) ? (_Float16)0.0f : (_Float16)d1[u];
        }
        *(half4_t*)&As[buf][r0][aoff] = h0;
        *(half4_t*)&As[buf][r1][aoff] = h1;
    };

#define BAR() do {                                             \
        asm volatile("s_waitcnt lgkmcnt(0)" ::: "memory");     \
        __builtin_amdgcn_sched_barrier(0);                     \
        __builtin_amdgcn_s_barrier();                          \
        __builtin_amdgcn_sched_barrier(0);                     \
    } while (0)

    // K-step body: cur = LDS buf literal; wrX = pending slice ks+1; ldX gets ks+2
#define KBODY(KS, CUR, WR0, WR1, LD0, LD1)                                     \
    {                                                                          \
        half8_t bq[8];                                                         \
        _Pragma("unroll")                                                      \
        for (int nf = 0; nf < 8; ++nf)                                         \
            bq[nf] = *(const half8_t*)(gB + nf * 8192 + (KS) * 512);           \
        if ((KS) + 2 < 16) ldA((KS) + 2, LD0, LD1);                            \
        half8_t af[4];                                                         \
        _Pragma("unroll")                                                      \
        for (int mf = 0; mf < 4; ++mf)                                         \
            af[mf] = *(const half8_t*)&As[CUR][wm * 64 + mf * 16 + l15][rch];  \
        _Pragma("unroll")                                                      \
        for (int nf = 0; nf < 8; ++nf) {                                       \
            _Pragma("unroll")                                                  \
            for (int mf = 0; mf < 4; ++mf)                                     \
                acc[mf][nf] = __builtin_amdgcn_mfma_f32_16x16x32_f16(          \
                    af[mf], bq[nf], acc[mf][nf], 0, 0, 0);                     \
        }                                                                      \
        if ((KS) + 1 < 16) wrA((CUR) ^ 1, WR0, WR1, (KS) + 1 == 15);           \
        BAR();                                                                 \
    }

    // prologue: slice 0 -> As[0]; slice 1 pending in po
    ldA(0, pe0, pe1);
    wrA(0, pe0, pe1, false);
    ldA(1, po0, po1);
    BAR();

    for (int kk = 0; kk < 16; kk += 2) {
        KBODY(kk,     0, po0, po1, pe0, pe1)
        KBODY(kk + 1, 1, pe0, pe1, po0, po1)
    }
#undef KBODY
#undef BAR

    // ---- epilogue: scores = sum_h v[h] * tanh(At + E) ----
    float vpv[8];
#pragma unroll
    for (int nf = 0; nf < 8; ++nf) vpv[nf] = vp[wn * 128 + nf * 16 + l15];

    float pj[4][4];
#pragma unroll
    for (int mf = 0; mf < 4; ++mf)
#pragma unroll
        for (int jj = 0; jj < 4; ++jj) pj[mf][jj] = 0.0f;

#pragma unroll
    for (int mf = 0; mf < 4; ++mf) {
#pragma unroll
        for (int nf = 0; nf < 8; ++nf) {
            int h = wn * 128 + nf * 16 + l15;
            f32x4 av = *(const f32x4*)(At + h * B_DIM + bloc + wm * 64 + mf * 16 + lq * 4);
#pragma unroll
            for (int jj = 0; jj < 4; ++jj) {
                float x  = acc[mf][nf][jj] + av[jj];
                float xc = fminf(fmaxf(x, -9.0f), 9.0f);
                float e  = __expf(2.0f * xc);
                float th = (e - 1.0f) / (e + 1.0f);
                pj[mf][jj] += vpv[nf] * th;
            }
        }
    }

#pragma unroll
    for (int mf = 0; mf < 4; ++mf)
#pragma unroll
        for (int jj = 0; jj < 4; ++jj) {
            float s = pj[mf][jj];
            s += __shfl_xor(s, 1); s += __shfl_xor(s, 2);
            s += __shfl_xor(s, 4); s += __shfl_xor(s, 8);
            if (l15 == 0) red[wn][wm * 64 + mf * 16 + lq * 4 + jj] = s;
        }
    __syncthreads();
    if (tid < 128) {
        float p = red[0][tid] + red[1][tid] + red[2][tid] + red[3][tid];
        sct[(size_t)(bloc + tid) * S_DIM + s_idx] = p;
    }
}

// ---- softmax over S per b; out[b][0][s] ----
__global__ void softmax_rows(const float* __restrict__ sct, float* __restrict__ out) {
    int b = blockIdx.x;
    int t = threadIdx.x;                  // 512 threads, one s each
    int lane = t & 63, w = t >> 6;
    float v = sct[(size_t)b * S_DIM + t];
    float m = v;
#pragma unroll
    for (int off = 1; off < 64; off <<= 1) m = fmaxf(m, __shfl_xor(m, off));
    __shared__ float sm[8], ss[8];
    if (lane == 0) sm[w] = m;
    __syncthreads();
    m = sm[0];
#pragma unroll
    for (int i = 1; i < 8; ++i) m = fmaxf(m, sm[i]);
    float e = __expf(v - m);
    float s = e;
#pragma unroll
    for (int off = 1; off < 64; off <<= 1) s += __shfl_xor(s, off);
    if (lane == 0) ss[w] = s;
    __syncthreads();
    s = ss[0];
#pragma unroll
    for (int i = 1; i < 8; ++i) s += ss[i];
    out[(size_t)b * S_DIM + t] = e / s;
}

extern "C" void kernel_launch(void* const* d_in, const int* in_sizes, int n_in,
                              void* d_out, int out_size, void* d_ws, size_t ws_size,
                              hipStream_t stream) {
    const float* hidden = (const float*)d_in[0];
    const float* enc    = (const float*)d_in[1];
    const float* W      = (const float*)d_in[2];
    const float* b_attn = (const float*)d_in[3];
    const float* v      = (const float*)d_in[4];
    float* out = (float*)d_out;

    char* ws = (char*)d_ws;
    _Float16* W2r = (_Float16*)(ws + WS_W2R);
    float*    At  = (float*)(ws + WS_AT);
    float*    vp  = (float*)(ws + WS_VP);
    float*    sct = (float*)(ws + WS_SC);

    prep_w2_v<<<512, 256, 0, stream>>>(W, v, W2r, vp);
    prep_A<<<256, 512, 0, stream>>>(hidden, W, b_attn, At);
    fused_attn_gemm<<<1024, 512, 0, stream>>>(enc, W2r, At, vp, sct);
    softmax_rows<<<256, 512, 0, stream>>>(sct, out);
}

// Round 7
// 214.164 us; speedup vs baseline: 1.0265x; 1.0265x over previous
//
#include <hip/hip_runtime.h>
#include <hip/hip_fp16.h>

#define S_DIM 512
#define B_DIM 256
#define H_DIM 500
#define M_DIM (S_DIM * B_DIM)     // 131072

typedef _Float16 half8_t __attribute__((ext_vector_type(8)));
typedef float    f32x4  __attribute__((ext_vector_type(4)));

// workspace layout (bytes)
#define WS_W2I 0                       // fp16 image [2][8][2048][8] = 512 KB
#define WS_AT  (512 * 1024)            // fp32 At[h][b] [512][256]   = 512 KB
#define WS_VP  (1024 * 1024)           // fp32 [512]
#define WS_SC  (1024 * 1024 + 4096)    // fp32 [2][256][512] partial scores = 1 MB

// ---- prep: W2 -> fp16 LDS-image: tile (nblk,kt): slot = nl*8 + (c^(nl&7)), 8 halves
__global__ void prep_w2_v(const float* __restrict__ W, const float* __restrict__ v,
                          _Float16* __restrict__ W2i, float* __restrict__ vp) {
    int idx = blockIdx.x * blockDim.x + threadIdx.x;   // 0..131071
#pragma unroll
    for (int r = 0; r < 2; ++r) {
        int e = idx + r * 131072;                      // 0..262143
        int n = e >> 9, k = e & 511;
        float val = (n < H_DIM && k < H_DIM) ? W[n * 1000 + 500 + k] : 0.0f;
        int nb = n >> 8, nl = n & 255, kt = k >> 6, c = (k >> 3) & 7, u = k & 7;
        int cL = c ^ (nl & 7);
        W2i[(((nb * 8 + kt) * 2048) + nl * 8 + cL) * 8 + u] = (_Float16)val;
    }
    if (idx < 512) vp[idx] = (idx < H_DIM) ? v[idx] : 0.0f;
}

// ---- prep: At[h][b] = b_attn[h] + hidden[b,:] . W1[h,:]  (exact fp32, transposed) ----
__global__ void prep_A(const float* __restrict__ hidden, const float* __restrict__ W,
                       const float* __restrict__ b_attn, float* __restrict__ At) {
    int b = blockIdx.x;
    int t = threadIdx.x;               // 0..511 = h
    __shared__ float hs[512];
    hs[t] = (t < H_DIM) ? hidden[b * H_DIM + t] : 0.0f;
    __syncthreads();
    float acc = 0.0f;
    if (t < H_DIM) {
        acc = b_attn[t];
        const float4* wr = (const float4*)(W + t * 1000);
        const float4* hr = (const float4*)hs;
#pragma unroll 5
        for (int i = 0; i < 125; ++i) {
            float4 w4 = wr[i], h4 = hr[i];
            acc += w4.x * h4.x + w4.y * h4.y + w4.z * h4.z + w4.w * h4.w;
        }
    }
    At[t * B_DIM + b] = acc;
}

// ---- main: 256(M) x 256(N) tile, BK=64, 512 thr = 8 waves (2M x 4N), wave 128x64.
// 8-phase-style schedule; all loads reg-staged (compiler counted-vmcnt, no drains).
__launch_bounds__(512, 2)
__global__ void fused_attn_gemm(const float* __restrict__ enc,
                                const _Float16* __restrict__ W2i,
                                const float* __restrict__ At,
                                const float* __restrict__ vp,
                                float* __restrict__ sct) {
    __shared__ _Float16 smem_h[65536];            // 128 KB: As [0..32768), Bs [32768..65536)
    _Float16* AsB = smem_h;                       // per buf 16384 halves ([256][64])
    _Float16* BsB = smem_h + 32768;

    const int tid  = threadIdx.x;
    const int lane = tid & 63;
    const int wid  = tid >> 6;            // 0..7
    const int wm   = wid >> 2;            // 0..1
    const int wn   = wid & 3;             // 0..3
    const int l15  = lane & 15;
    const int lq   = lane >> 4;           // 0..3

    // XCD-chunked work swizzle: sibling n-pair lands on same XCD, adjacent in time
    const int wg   = (blockIdx.x & 7) * 128 + (blockIdx.x >> 3);
    const int mblk = wg >> 1;             // = s index (0..511)
    const int nblk = wg & 1;
    const int m0   = mblk * 256;

    // A staging: thread -> row ra (0..127) within half, col chunk ja (16 floats)
    const int ra = tid >> 2;
    const int ja = tid & 3;
    const size_t rowA0 = (size_t)(m0 + ra) * H_DIM;
    const size_t rowA1 = (size_t)(m0 + 128 + ra) * H_DIM;
    const int colb = ja * 16;
    const int cL0 = ((ja * 2) ^ (ra & 7)) * 8;        // swizzled LDS half-offsets
    const int cL1 = ((ja * 2 + 1) ^ (ra & 7)) * 8;

    // B staging: linear copy of pre-swizzled image
    const _Float16* gWb = W2i + ((size_t)nblk * 8) * 2048 * 8 + (size_t)tid * 8;

    f32x4 acc[8][4];
#pragma unroll
    for (int a = 0; a < 8; ++a)
#pragma unroll
        for (int b = 0; b < 4; ++b) acc[a][b] = 0;

    f32x4 la0[4], la1[4];
    half8_t bst[4];

    auto issueB = [&](int kt) {
        const _Float16* g = gWb + (size_t)kt * 2048 * 8;
#pragma unroll
        for (int i = 0; i < 4; ++i) bst[i] = *(const half8_t*)(g + i * 512 * 8);
    };
    auto writeB = [&](int buf) {
#pragma unroll
        for (int i = 0; i < 4; ++i)
            *(half8_t*)(BsB + buf * 16384 + (tid + i * 512) * 8) = bst[i];
    };
    auto issueA = [&](int kt, int h, f32x4* l) {
        const float* g = enc + (h ? rowA1 : rowA0);
        if (kt < 7) {
            const float* gk = g + kt * 64 + colb;
#pragma unroll
            for (int i = 0; i < 4; ++i) l[i] = *(const f32x4*)(gk + i * 4);
        } else {
#pragma unroll
            for (int i = 0; i < 4; ++i) {
                int cc = 448 + colb + i * 4;
                cc = cc > 496 ? 496 : cc;              // clamp; masked at write
                l[i] = *(const f32x4*)(g + cc);
            }
        }
    };
    auto writeA = [&](int buf, int h, const f32x4* l, bool tail) {
        half8_t h0, h1;
#pragma unroll
        for (int u = 0; u < 4; ++u) {
            h0[u] = (_Float16)l[0][u]; h0[u + 4] = (_Float16)l[1][u];
            h1[u] = (_Float16)l[2][u]; h1[u + 4] = (_Float16)l[3][u];
        }
        if (tail) {
#pragma unroll
            for (int u = 0; u < 8; ++u) {
                if (448 + ja * 16 + u >= H_DIM)     h0[u] = (_Float16)0.0f;
                if (448 + ja * 16 + 8 + u >= H_DIM) h1[u] = (_Float16)0.0f;
            }
        }
        _Float16* base = AsB + buf * 16384 + (h * 128 + ra) * 64;
        *(half8_t*)(base + cL0) = h0;
        *(half8_t*)(base + cL1) = h1;
    };

#define PHASE(BUF, MH, KS, STAGE)                                              \
    {                                                                          \
        half8_t afv[4], bfv[4];                                                \
        const int rch = (((KS) * 4 + lq) ^ (l15 & 7)) * 8;                     \
        _Pragma("unroll")                                                      \
        for (int nf = 0; nf < 4; ++nf)                                         \
            bfv[nf] = *(const half8_t*)(BsB + (BUF) * 16384 +                  \
                        (wn * 64 + nf * 16 + l15) * 64 + rch);                 \
        _Pragma("unroll")                                                      \
        for (int mf = 0; mf < 4; ++mf)                                         \
            afv[mf] = *(const half8_t*)(AsB + (BUF) * 16384 +                  \
                        (wm * 128 + (MH) * 64 + mf * 16 + l15) * 64 + rch);    \
        STAGE                                                                  \
        asm volatile("s_barrier" ::: "memory");                                \
        __builtin_amdgcn_s_setprio(1);                                         \
        _Pragma("unroll")                                                      \
        for (int nf = 0; nf < 4; ++nf) {                                       \
            _Pragma("unroll")                                                  \
            for (int mf = 0; mf < 4; ++mf)                                     \
                acc[(MH) * 4 + mf][nf] = __builtin_amdgcn_mfma_f32_16x16x32_f16( \
                    afv[mf], bfv[nf], acc[(MH) * 4 + mf][nf], 0, 0, 0);        \
        }                                                                      \
        __builtin_amdgcn_s_setprio(0);                                         \
    }

#define TILE(KT, BUF)                                                          \
    {                                                                          \
        const bool st = (KT) < 7;                                              \
        const bool tl = (KT) + 1 == 7;                                         \
        PHASE(BUF, 0, 0, { if (st) { issueB((KT) + 1); issueA((KT) + 1, 0, la0); } }) \
        __builtin_amdgcn_s_barrier();                                          \
        PHASE(BUF, 1, 0, { if (st) { issueA((KT) + 1, 1, la1); } })            \
        __builtin_amdgcn_s_barrier();                                          \
        PHASE(BUF, 0, 1, { if (st) { writeB((BUF) ^ 1); writeA((BUF) ^ 1, 0, la0, tl); } }) \
        __builtin_amdgcn_s_barrier();                                          \
        PHASE(BUF, 1, 1, { if (st) { writeA((BUF) ^ 1, 1, la1, tl); } })       \
        asm volatile("s_waitcnt lgkmcnt(0)\n\ts_barrier" ::: "memory");        \
    }

    // prologue: stage tile 0 into buf 0
    issueB(0); issueA(0, 0, la0); issueA(0, 1, la1);
    writeB(0); writeA(0, 0, la0, false); writeA(0, 1, la1, false);
    asm volatile("s_waitcnt lgkmcnt(0)\n\ts_barrier" ::: "memory");

    for (int kt = 0; kt < 8; kt += 2) {
        TILE(kt, 0)
        TILE(kt + 1, 1)
    }
#undef TILE
#undef PHASE

    // ---- epilogue: scores = sum_h v[h] * tanh(At + E) ----
    const int n0 = nblk * 256;
    float vpv[4];
#pragma unroll
    for (int nf = 0; nf < 4; ++nf) vpv[nf] = vp[n0 + wn * 64 + nf * 16 + l15];

    float pj[8][4];
#pragma unroll
    for (int F = 0; F < 8; ++F)
#pragma unroll
        for (int j = 0; j < 4; ++j) pj[F][j] = 0.0f;

#pragma unroll
    for (int F = 0; F < 8; ++F) {
#pragma unroll
        for (int nf = 0; nf < 4; ++nf) {
            int h = n0 + wn * 64 + nf * 16 + l15;
            f32x4 av = *(const f32x4*)(At + h * B_DIM + wm * 128 + F * 16 + lq * 4);
#pragma unroll
            for (int j = 0; j < 4; ++j) {
                float x  = acc[F][nf][j] + av[j];
                float xc = fminf(fmaxf(x, -9.0f), 9.0f);
                float e  = __expf(2.0f * xc);
                float th = (e - 1.0f) / (e + 1.0f);
                pj[F][j] += vpv[nf] * th;
            }
        }
    }

    float* red = (float*)smem_h;          // [4][256] — aliases As (safe post-loop)
#pragma unroll
    for (int F = 0; F < 8; ++F)
#pragma unroll
        for (int j = 0; j < 4; ++j) {
            float s = pj[F][j];
            s += __shfl_xor(s, 1); s += __shfl_xor(s, 2);
            s += __shfl_xor(s, 4); s += __shfl_xor(s, 8);
            if (l15 == 0) red[wn * 256 + wm * 128 + F * 16 + lq * 4 + j] = s;
        }
    __syncthreads();
    if (tid < 256) {
        float p = red[tid] + red[256 + tid] + red[512 + tid] + red[768 + tid];
        sct[(size_t)nblk * M_DIM + (size_t)tid * S_DIM + mblk] = p;
    }
}

// ---- softmax over S per b, summing the 2 N-partials; out[b][0][s] ----
__global__ void softmax_rows(const float* __restrict__ sct, float* __restrict__ out) {
    int b = blockIdx.x;
    int t = threadIdx.x;                  // 512 threads, one s each
    int lane = t & 63, w = t >> 6;
    size_t idx = (size_t)b * S_DIM + t;
    float v = sct[idx] + sct[idx + M_DIM];
    float m = v;
#pragma unroll
    for (int off = 1; off < 64; off <<= 1) m = fmaxf(m, __shfl_xor(m, off));
    __shared__ float sm[8], ss[8];
    if (lane == 0) sm[w] = m;
    __syncthreads();
    m = sm[0];
#pragma unroll
    for (int i = 1; i < 8; ++i) m = fmaxf(m, sm[i]);
    float e = __expf(v - m);
    float s = e;
#pragma unroll
    for (int off = 1; off < 64; off <<= 1) s += __shfl_xor(s, off);
    if (lane == 0) ss[w] = s;
    __syncthreads();
    s = ss[0];
#pragma unroll
    for (int i = 1; i < 8; ++i) s += ss[i];
    out[(size_t)b * S_DIM + t] = e / s;
}

extern "C" void kernel_launch(void* const* d_in, const int* in_sizes, int n_in,
                              void* d_out, int out_size, void* d_ws, size_t ws_size,
                              hipStream_t stream) {
    const float* hidden = (const float*)d_in[0];
    const float* enc    = (const float*)d_in[1];
    const float* W      = (const float*)d_in[2];
    const float* b_attn = (const float*)d_in[3];
    const float* v      = (const float*)d_in[4];
    float* out = (float*)d_out;

    char* ws = (char*)d_ws;
    _Float16* W2i = (_Float16*)(ws + WS_W2I);
    float*    At  = (float*)(ws + WS_AT);
    float*    vp  = (float*)(ws + WS_VP);
    float*    sct = (float*)(ws + WS_SC);

    prep_w2_v<<<512, 256, 0, stream>>>(W, v, W2i, vp);
    prep_A<<<256, 512, 0, stream>>>(hidden, W, b_attn, At);
    fused_attn_gemm<<<1024, 512, 0, stream>>>(enc, W2i, At, vp, sct);
    softmax_rows<<<256, 512, 0, stream>>>(sct, out);
}